// Round 2
// baseline (1107.320 us; speedup 1.0000x reference)
//
#include <hip/hip_runtime.h>

namespace {

constexpr int NJ = 24;

struct Xf { float r[9]; float t[3]; };

__device__ __forceinline__ void rodrigues(float x, float y, float z, float R[9]) {
    float n2 = x*x + y*y + z*z + 1e-8f;
    float th = sqrtf(n2);
    float inv = 1.0f / th;
    float ax = x * inv, ay = y * inv, az = z * inv;
    float s = __sinf(th);
    float c = __cosf(th);
    float C = 1.0f - c;
    float aa = ax*ax + ay*ay + az*az;
    float xy = C*ax*ay, xz = C*ax*az, yz = C*ay*az;
    float sx = s*ax, sy = s*ay, sz = s*az;
    R[0] = 1.0f + C*(ax*ax - aa);
    R[1] = xy - sz;
    R[2] = xz + sy;
    R[3] = xy + sz;
    R[4] = 1.0f + C*(ay*ay - aa);
    R[5] = yz - sx;
    R[6] = xz - sy;
    R[7] = yz + sx;
    R[8] = 1.0f + C*(az*az - aa);
}

// One chain joint: rodrigues + compose + buffer kp + pair-line l2ws/skts emit.
// Even J: stash world transform (R, t-with-pelvis) in st[12].
// Odd J:  write BOTH joints' l2ws (one full 128B line) and skts (one full
//         128B line) as back-to-back float4 bursts — every touched L2 line is
//         fully dirtied by a single wave-instruction group, so it is written
//         back to HBM exactly once (no partial-line RMW amplification).
template<int J>
__device__ __forceinline__ Xf jstep(const Xf& P, const float* __restrict__ bn,
                                    const float (*sdt)[3],
                                    float* __restrict__ out, size_t B, int b,
                                    float px, float py, float pz,
                                    float* __restrict__ kpv, float* __restrict__ st) {
    float Rl[9];
    rodrigues(bn[3*J+0], bn[3*J+1], bn[3*J+2], Rl);
    Xf C;
    if constexpr (J == 0) {
        #pragma unroll
        for (int i = 0; i < 9; ++i) C.r[i] = Rl[i];
        C.t[0] = sdt[0][0]; C.t[1] = sdt[0][1]; C.t[2] = sdt[0][2];
    } else {
        float d0 = sdt[J][0], d1 = sdt[J][1], d2 = sdt[J][2];
        C.r[0] = P.r[0]*Rl[0] + P.r[1]*Rl[3] + P.r[2]*Rl[6];
        C.r[1] = P.r[0]*Rl[1] + P.r[1]*Rl[4] + P.r[2]*Rl[7];
        C.r[2] = P.r[0]*Rl[2] + P.r[1]*Rl[5] + P.r[2]*Rl[8];
        C.r[3] = P.r[3]*Rl[0] + P.r[4]*Rl[3] + P.r[5]*Rl[6];
        C.r[4] = P.r[3]*Rl[1] + P.r[4]*Rl[4] + P.r[5]*Rl[7];
        C.r[5] = P.r[3]*Rl[2] + P.r[4]*Rl[5] + P.r[5]*Rl[8];
        C.r[6] = P.r[6]*Rl[0] + P.r[7]*Rl[3] + P.r[8]*Rl[6];
        C.r[7] = P.r[6]*Rl[1] + P.r[7]*Rl[4] + P.r[8]*Rl[7];
        C.r[8] = P.r[6]*Rl[2] + P.r[7]*Rl[5] + P.r[8]*Rl[8];
        C.t[0] = P.r[0]*d0 + P.r[1]*d1 + P.r[2]*d2 + P.t[0];
        C.t[1] = P.r[3]*d0 + P.r[4]*d1 + P.r[5]*d2 + P.t[1];
        C.t[2] = P.r[6]*d0 + P.r[7]*d1 + P.r[8]*d2 + P.t[2];
    }
    float tx = C.t[0] + px, ty = C.t[1] + py, tz = C.t[2] + pz;
    // kp buffered in registers (constant indices), flushed in one burst later.
    kpv[3*J+0] = tx; kpv[3*J+1] = ty; kpv[3*J+2] = tz;
    if constexpr ((J & 1) == 0) {
        st[0]=C.r[0]; st[1]=C.r[1]; st[2]=C.r[2];
        st[3]=C.r[3]; st[4]=C.r[4]; st[5]=C.r[5];
        st[6]=C.r[6]; st[7]=C.r[7]; st[8]=C.r[8];
        st[9]=tx; st[10]=ty; st[11]=tz;
    } else {
        constexpr int E = J - 1;
        // l2ws: [B,24,4,4] at float offset B*528; pair (E,J) = one 128B line.
        float4* lp = reinterpret_cast<float4*>(out + B*528 + (size_t)b*384 + E*16);
        lp[0] = make_float4(st[0], st[1], st[2], st[9]);
        lp[1] = make_float4(st[3], st[4], st[5], st[10]);
        lp[2] = make_float4(st[6], st[7], st[8], st[11]);
        lp[3] = make_float4(0.f, 0.f, 0.f, 1.f);
        lp[4] = make_float4(C.r[0], C.r[1], C.r[2], tx);
        lp[5] = make_float4(C.r[3], C.r[4], C.r[5], ty);
        lp[6] = make_float4(C.r[6], C.r[7], C.r[8], tz);
        lp[7] = make_float4(0.f, 0.f, 0.f, 1.f);
        // skts = [R^T | -R^T t]: pair (E,J) = one 128B line.
        float4* sp = reinterpret_cast<float4*>(out + B*144 + (size_t)b*384 + E*16);
        sp[0] = make_float4(st[0], st[3], st[6], -(st[0]*st[9] + st[3]*st[10] + st[6]*st[11]));
        sp[1] = make_float4(st[1], st[4], st[7], -(st[1]*st[9] + st[4]*st[10] + st[7]*st[11]));
        sp[2] = make_float4(st[2], st[5], st[8], -(st[2]*st[9] + st[5]*st[10] + st[8]*st[11]));
        sp[3] = make_float4(0.f, 0.f, 0.f, 1.f);
        sp[4] = make_float4(C.r[0], C.r[3], C.r[6], -(C.r[0]*tx + C.r[3]*ty + C.r[6]*tz));
        sp[5] = make_float4(C.r[1], C.r[4], C.r[7], -(C.r[1]*tx + C.r[4]*ty + C.r[7]*tz));
        sp[6] = make_float4(C.r[2], C.r[5], C.r[8], -(C.r[2]*tx + C.r[5]*ty + C.r[8]*tz));
        sp[7] = make_float4(0.f, 0.f, 0.f, 1.f);
    }
    return C;
}

__device__ const int g_par[NJ] = {0,0,0,0,1,2,3,4,5,6,7,8,9,9,9,12,13,14,16,17,18,19,20,21};

__global__ __launch_bounds__(256, 2)
void pose_kernel(const float* __restrict__ pelvis,
                 const float* __restrict__ bones,
                 const float* __restrict__ rest,
                 const int* __restrict__ idxs,
                 float* __restrict__ out, int Bn)
{
    __shared__ float sdt[NJ][3];
    const int tid = threadIdx.x;
    if (tid < NJ) {
        if (tid == 0) {
            sdt[0][0] = rest[0]; sdt[0][1] = rest[1]; sdt[0][2] = rest[2];
        } else {
            int p = g_par[tid];
            sdt[tid][0] = rest[tid*3+0] - rest[p*3+0];
            sdt[tid][1] = rest[tid*3+1] - rest[p*3+1];
            sdt[tid][2] = rest[tid*3+2] - rest[p*3+2];
        }
    }
    __syncthreads();

    int b = blockIdx.x * 256 + tid;
    if (b >= Bn) return;
    size_t B = (size_t)Bn;

    int idx = idxs[b];
    float px = pelvis[(size_t)idx*3+0];
    float py = pelvis[(size_t)idx*3+1];
    float pz = pelvis[(size_t)idx*3+2];

    // Gather the 24x3 bone vector (288B contiguous) into registers, forwarding
    // straight to the `bone` output as a tight per-thread float4 burst.
    float bn[72];
    const float4* bsrc = reinterpret_cast<const float4*>(bones + (size_t)idx*72);
    float4* bdst = reinterpret_cast<float4*>(out + B*72 + (size_t)b*72);
    #pragma unroll
    for (int k = 0; k < 18; ++k) {
        float4 v = bsrc[k];
        bdst[k] = v;
        bn[4*k+0] = v.x; bn[4*k+1] = v.y; bn[4*k+2] = v.z; bn[4*k+3] = v.w;
    }

    // ---- rots pass: local rotations only (no chain dependence). Recompute
    // rodrigues and flush in 3 chunks of 8 joints = 288B contiguous bursts.
    {
        float* rout = out + B*912 + (size_t)b*216;
        #pragma unroll
        for (int c = 0; c < 3; ++c) {
            alignas(16) float rl[72];
            #pragma unroll
            for (int j = 0; j < 8; ++j) {
                float R[9];
                rodrigues(bn[(c*8+j)*3+0], bn[(c*8+j)*3+1], bn[(c*8+j)*3+2], R);
                #pragma unroll
                for (int i = 0; i < 9; ++i) rl[j*9+i] = R[i];
            }
            float4* rq = reinterpret_cast<float4*>(rout + c*72);
            #pragma unroll
            for (int k = 0; k < 18; ++k)
                rq[k] = *reinterpret_cast<const float4*>(&rl[4*k]);
        }
    }

    // ---- chain pass: increasing-J (parents precede children). kp buffered in
    // registers; l2ws/skts written as full 128B-line pair bursts inside jstep.
    alignas(16) float kpv[72];
    float st[12];
    Xf dummy{};
    Xf x0  = jstep<0>(dummy, bn, sdt, out, B, b, px, py, pz, kpv, st);
    Xf x1  = jstep<1>(x0,  bn, sdt, out, B, b, px, py, pz, kpv, st);
    Xf x2  = jstep<2>(x0,  bn, sdt, out, B, b, px, py, pz, kpv, st);
    Xf x3  = jstep<3>(x0,  bn, sdt, out, B, b, px, py, pz, kpv, st);
    Xf x4  = jstep<4>(x1,  bn, sdt, out, B, b, px, py, pz, kpv, st);
    Xf x5  = jstep<5>(x2,  bn, sdt, out, B, b, px, py, pz, kpv, st);
    Xf x6  = jstep<6>(x3,  bn, sdt, out, B, b, px, py, pz, kpv, st);
    Xf x7  = jstep<7>(x4,  bn, sdt, out, B, b, px, py, pz, kpv, st);
    Xf x8  = jstep<8>(x5,  bn, sdt, out, B, b, px, py, pz, kpv, st);
    Xf x9  = jstep<9>(x6,  bn, sdt, out, B, b, px, py, pz, kpv, st);
    (void)   jstep<10>(x7,  bn, sdt, out, B, b, px, py, pz, kpv, st);
    (void)   jstep<11>(x8,  bn, sdt, out, B, b, px, py, pz, kpv, st);
    Xf x12 = jstep<12>(x9,  bn, sdt, out, B, b, px, py, pz, kpv, st);
    Xf x13 = jstep<13>(x9,  bn, sdt, out, B, b, px, py, pz, kpv, st);
    Xf x14 = jstep<14>(x9,  bn, sdt, out, B, b, px, py, pz, kpv, st);
    (void)   jstep<15>(x12, bn, sdt, out, B, b, px, py, pz, kpv, st);
    Xf x16 = jstep<16>(x13, bn, sdt, out, B, b, px, py, pz, kpv, st);
    Xf x17 = jstep<17>(x14, bn, sdt, out, B, b, px, py, pz, kpv, st);
    Xf x18 = jstep<18>(x16, bn, sdt, out, B, b, px, py, pz, kpv, st);
    Xf x19 = jstep<19>(x17, bn, sdt, out, B, b, px, py, pz, kpv, st);
    Xf x20 = jstep<20>(x18, bn, sdt, out, B, b, px, py, pz, kpv, st);
    Xf x21 = jstep<21>(x19, bn, sdt, out, B, b, px, py, pz, kpv, st);
    (void)   jstep<22>(x20, bn, sdt, out, B, b, px, py, pz, kpv, st);
    (void)   jstep<23>(x21, bn, sdt, out, B, b, px, py, pz, kpv, st);

    // kp flush: one tight 288B contiguous burst per thread.
    float4* kq = reinterpret_cast<float4*>(out + (size_t)b*72);
    #pragma unroll
    for (int k = 0; k < 18; ++k)
        kq[k] = *reinterpret_cast<const float4*>(&kpv[4*k]);
}

} // namespace

extern "C" void kernel_launch(void* const* d_in, const int* in_sizes, int n_in,
                              void* d_out, int out_size, void* d_ws, size_t ws_size,
                              hipStream_t stream) {
    const float* pelvis = (const float*)d_in[0];
    const float* bones  = (const float*)d_in[1];
    const float* rest   = (const float*)d_in[2];
    const int*   idxs   = (const int*)d_in[3];
    float* out = (float*)d_out;
    int B = in_sizes[3];
    int blocks = (B + 255) / 256;
    hipLaunchKernelGGL(pose_kernel, dim3(blocks), dim3(256), 0, stream,
                       pelvis, bones, rest, idxs, out, B);
}